// Round 14
// baseline (67.791 us; speedup 1.0000x reference)
//
#include <hip/hip_runtime.h>
#include <hip/hip_bf16.h>

// Problem constants (from reference)
#define BB   16
#define NS   1024
#define NT   4096
#define CIN  256
#define CSK  64
#define HD   256           // hidden dim / output cols
#define K1   (CIN + CSK)   // 320
#define MTOT (BB * NT)     // 65536

typedef __attribute__((ext_vector_type(4))) float f32x4;
typedef __attribute__((ext_vector_type(8))) __bf16 bf16x8;
typedef __attribute__((ext_vector_type(4))) unsigned short ushort4v;

// ws layout (bytes)
#define W1F_OFF 0u                    // bf16[320*256]    = 163840
#define W2F_OFF 163840u               // bf16[256*256]    = 131072

static __device__ __forceinline__ unsigned short f2bf(float f) {
    union { float f; unsigned int u; } v; v.f = f;
    unsigned int r = (v.u + 0x7FFFu + ((v.u >> 16) & 1u)) >> 16;
    return (unsigned short)r;
}
// HW bf16 convert (v_cvt_pk_bf16_f32, RNE — bit-identical to f2bf on finite)
static __device__ __forceinline__ unsigned short f2bf_hw(float f) {
    union { __bf16 b; unsigned short u; } v; v.b = (__bf16)f;
    return v.u;
}

// ---- prep: W1/W2 swizzle into MFMA B-fragment order + out tail section ----
// Wf layout: Wf[kblk][n(16)][lane(64)][8]
//   k = kblk*32 + (lane>>4)*8 + j ; col = n*16 + (lane&15)
#define PREP_B1 (K1 * HD / 256)         // 320 blocks for W1f
#define PREP_B2 (HD * HD / 256)         // 256 blocks for W2f
#define PREP_B3 ((MTOT * 3) / 256)      // 768 blocks for tail
__global__ __launch_bounds__(256) void prep_kernel(
    const float* __restrict__ W1, const float* __restrict__ W2,
    const float* __restrict__ pos_skip,
    unsigned short* __restrict__ W1f, unsigned short* __restrict__ W2f,
    float* __restrict__ out)
{
    const int b = blockIdx.x;
    if (b < PREP_B1 + PREP_B2) {
        const bool is1 = b < PREP_B1;
        const int id = (is1 ? b : b - PREP_B1) * 256 + threadIdx.x;
        const int j    = id & 7;
        const int lane = (id >> 3) & 63;
        const int n    = (id >> 9) & 15;
        const int kblk = id >> 13;
        const int k   = kblk * 32 + (lane >> 4) * 8 + j;
        const int col = n * 16 + (lane & 15);
        if (is1) W1f[id] = f2bf(W1[(size_t)k * HD + col]);
        else     W2f[id] = f2bf(W2[(size_t)k * HD + col]);
    } else {
        const int i = (b - PREP_B1 - PREP_B2) * 256 + threadIdx.x;
        const size_t o1 = (size_t)MTOT * HD;
        out[o1 + i] = pos_skip[i];                                  // i < MTOT*3
        if (i < MTOT) out[o1 + (size_t)MTOT * 3 + i] = (float)(i >> 12);
    }
}

// ===== MEGAKERNEL: kNN + interp-gather + GEMM1 + GEMM2 per 64-row block =====
// Barrier-minimal (5 barriers). B operands stream L2->VGPR (no ldsB).
// ldsA = exactly 40960 B -> 4 blocks/CU. kNN: pure-f32 (d,idx) pair-merge
// top-3 (no f64) — strict-< comparators give exact lex-(d,idx) selection
// (resident always has lower idx than incoming within a lane; cross-lane
// merge uses explicit tie-aware compares).
__global__ __launch_bounds__(256, 4) void fp_fused_kernel(
    const float* __restrict__ x, const float* __restrict__ x_skip,
    const float* __restrict__ pos, const float* __restrict__ pos_skip,
    const unsigned short* __restrict__ W1f, const unsigned short* __restrict__ W2f,
    const float* __restrict__ b1, const float* __restrict__ b2,
    float* __restrict__ out)
{
    __shared__ __align__(16) unsigned short ldsA[10 * 4 * 512]; // 40 KB exactly

    const int tid = threadIdx.x;
    const int w = tid >> 6, lane = tid & 63;
    const int l15 = lane & 15, lk = lane >> 4;

    // cloud<->XCD affinity (bijective on [0,1024))
    const int bid   = blockIdx.x;
    const int xcd   = bid & 7;
    const int j     = bid >> 3;                 // 0..127
    const int cloud = xcd + 8 * (j >> 6);       // 0..15
    const int bm    = cloud * 64 + (j & 63);    // 64-row block index

    // B source pointers; prefetch GEMM1's first 4 B-frags before kNN (hides
    // L2 latency at phase-3 start; 16 VGPRs held through phase 1/2).
    const unsigned short* w1p = W1f + (w * 4) * 512 + lane * 8;
    const unsigned short* w2p = W2f + (w * 4) * 512 + lane * 8;
    bf16x8 bpre[4];
    #pragma unroll
    for (int nf = 0; nf < 4; ++nf)
        bpre[nf] = *(const bf16x8*)(w1p + nf * 512);

    // ---------------- phase 1: kNN for this block's 64 queries ----------------
    // Query q = tid>>2, partition p = tid&3; pair-processing (s, s+4).
    int   myi0, myi1, myi2;
    float myw0, myw1, myw2;
    {
        float4* sp = (float4*)ldsA;             // 16 KB overlay, dead after phase 1
        const float* pc = pos + (size_t)cloud * NS * 3;
        for (int i = tid; i < NS; i += 256)
            sp[i] = make_float4(pc[i * 3 + 0], pc[i * 3 + 1], pc[i * 3 + 2], 0.f);
        __syncthreads();                                            // [1]

        const int p  = tid & 3;
        const int rg = bm * 64 + (tid >> 2);
        const float qx = pos_skip[rg * 3 + 0];
        const float qy = pos_skip[rg * 3 + 1];
        const float qz = pos_skip[rg * 3 + 2];

        float d0 = 1e30f, d1k = 1e30f, d2k = 1e30f;
        unsigned i0 = 0, i1 = 0, i2 = 0;
        #pragma unroll 2
        for (int ii = 0; ii < NS / 8; ++ii) {
            const int slo = ii * 8 + p;
            const int shi = slo + 4;
            float4 ca = sp[slo];
            float4 cb = sp[shi];
            float dxa = qx - ca.x, dya = qy - ca.y, dza = qz - ca.z;
            float da = dxa * dxa + dya * dya + dza * dza;
            float dxb = qx - cb.x, dyb = qy - cb.y, dzb = qz - cb.z;
            float db = dxb * dxb + dyb * dyb + dzb * dzb;
            // pair sort (tie keeps a = lower s)
            bool cs = db < da;
            float    dlo = cs ? db : da,           dhi = cs ? da : db;
            unsigned ilo = cs ? (unsigned)shi : (unsigned)slo;
            unsigned ihi = cs ? (unsigned)slo : (unsigned)shi;
            // merge sorted pair into sorted (d0<=d1<=d2): 4-comparator network
            bool c0 = dlo < d0;                        // comparator (b0, lo)
            float    x0d = c0 ? dlo : d0,  x1d = c0 ? d0 : dlo;
            unsigned x0i = c0 ? ilo : i0,  x1i = c0 ? i0 : ilo;
            bool cy = dhi < d1k;                       // y0 = min(b1, hi)
            float    y0d = cy ? dhi : d1k;
            unsigned y0i = cy ? ihi : i1;
            bool cr = y0d < x1d;                       // r1=min(x1,y0), t=max
            float    r1d = cr ? y0d : x1d, td = cr ? x1d : y0d;
            unsigned r1i = cr ? y0i : x1i; unsigned ti = cr ? x1i : y0i;
            bool c2 = td < d2k;                        // r2 = min(t, b2)
            float    r2d = c2 ? td : d2k;
            unsigned r2i = c2 ? ti : i2;
            d0 = x0d; i0 = x0i; d1k = r1d; i1 = r1i; d2k = r2d; i2 = r2i;
        }
        // cross-lane merge over partitions (xor 1, 2) — tie-aware (d, idx) lex
        #pragma unroll
        for (int m = 1; m <= 2; m <<= 1) {
            float    od0 = __shfl_xor(d0, m, 64);
            float    od1 = __shfl_xor(d1k, m, 64);
            float    od2 = __shfl_xor(d2k, m, 64);
            unsigned oi0 = (unsigned)__shfl_xor((int)i0, m, 64);
            unsigned oi1 = (unsigned)__shfl_xor((int)i1, m, 64);
            unsigned oi2 = (unsigned)__shfl_xor((int)i2, m, 64);
            float od[3] = { od0, od1, od2 };
            unsigned oi[3] = { oi0, oi1, oi2 };
            #pragma unroll
            for (int e = 0; e < 3; ++e) {
                float dd = od[e]; unsigned ss = oi[e];
                bool lt0 = (dd < d0)  || (dd == d0  && ss < i0);
                bool lt1 = (dd < d1k) || (dd == d1k && ss < i1);
                bool lt2 = (dd < d2k) || (dd == d2k && ss < i2);
                d2k = lt1 ? d1k : (lt2 ? dd : d2k);  i2 = lt1 ? i1 : (lt2 ? ss : i2);
                d1k = lt0 ? d0  : (lt1 ? dd : d1k);  i1 = lt0 ? i0 : (lt1 ? ss : i1);
                d0  = lt0 ? dd  : d0;                i0 = lt0 ? ss : i0;
            }
        }
        // all 4 lanes hold the exact top-3 (total order -> identical results)
        myi0 = (int)i0; myi1 = (int)i1; myi2 = (int)i2;
        float w0 = 1.f / fmaxf(d0, 1e-16f);
        float w1 = 1.f / fmaxf(d1k, 1e-16f);
        float w2 = 1.f / fmaxf(d2k, 1e-16f);
        float inv = 1.f / (w0 + w1 + w2);
        myw0 = w0 * inv; myw1 = w1 * inv; myw2 = w2 * inv;
        __syncthreads();   // [2] sp reads complete (ldsA about to be overwritten)
    }

    // ------- phase 2: one-shot A gather/blend (all 320 cols -> ldsA) -------
    // Row w*16+r16's kNN result lives in lane 4*r16 of THIS wave.
    {
        const int cb  = cloud * NS;             // cloud base row in x
        const int kbm = lane >> 3;              // main: c=4*lane -> kb (0..7)
        const int lkm = (lane >> 1) & 3;
        const int em  = lane & 1;
        const int kbs = 8 + (lane >> 5);        // skip: c=256+lane -> kb (8,9)
        const int lks = (lane >> 3) & 3;
        const int jjs = lane & 7;
        #pragma unroll
        for (int r16 = 0; r16 < 16; ++r16) {
            const int src = r16 * 4;
            const int i0 = cb + __shfl(myi0, src, 64);
            const int i1 = cb + __shfl(myi1, src, 64);
            const int i2 = cb + __shfl(myi2, src, 64);
            const float w0 = __shfl(myw0, src, 64);
            const float w1 = __shfl(myw1, src, 64);
            const float w2 = __shfl(myw2, src, 64);
            const int row = w * 16 + r16;
            const int rg  = bm * 64 + row;
            f32x4 a = *(const f32x4*)(x + (size_t)i0 * CIN + lane * 4);
            f32x4 b = *(const f32x4*)(x + (size_t)i1 * CIN + lane * 4);
            f32x4 c = *(const f32x4*)(x + (size_t)i2 * CIN + lane * 4);
            float s = x_skip[(size_t)rg * CSK + lane];
            f32x4 r = a * w0 + b * w1 + c * w2;
            int H = ((kbm * 4 + w) * 64 + (r16 + 16 * lkm)) * 8 + 4 * em;
            H ^= (kbm & 7) << 3;
            ushort4v o4 = { f2bf_hw(r[0]), f2bf_hw(r[1]), f2bf_hw(r[2]), f2bf_hw(r[3]) };
            *(ushort4v*)&ldsA[H] = o4;
            int H2 = ((kbs * 4 + w) * 64 + (r16 + 16 * lks)) * 8 + jjs;
            H2 ^= (kbs & 7) << 3;
            ldsA[H2] = f2bf_hw(s);
        }
    }
    __syncthreads();   // [3] A tile complete

    // ---------------- phase 3: GEMM1 k-loop, barrier-free (B: L2->VGPR) ----------------
    f32x4 acc[4][4];
    #pragma unroll
    for (int mf = 0; mf < 4; ++mf)
        #pragma unroll
        for (int nf = 0; nf < 4; ++nf)
            acc[mf][nf] = f32x4{0.f, 0.f, 0.f, 0.f};

    {
        bf16x8 bc[4], bn[4];
        #pragma unroll
        for (int nf = 0; nf < 4; ++nf) bc[nf] = bpre[nf];
        #pragma unroll
        for (int kb = 0; kb < 10; ++kb) {
            if (kb < 9) {
                #pragma unroll
                for (int nf = 0; nf < 4; ++nf)
                    bn[nf] = *(const bf16x8*)(w1p + (size_t)(kb + 1) * 8192 + nf * 512);
            }
            bf16x8 a[4];
            #pragma unroll
            for (int mf = 0; mf < 4; ++mf) {
                int aoff = ((kb * 4 + mf) * 64 + lane) * 8;
                aoff ^= (kb & 7) << 3;
                a[mf] = *(const bf16x8*)&ldsA[aoff];
            }
            #pragma unroll
            for (int mf = 0; mf < 4; ++mf)
                #pragma unroll
                for (int nf = 0; nf < 4; ++nf)
                    acc[mf][nf] = __builtin_amdgcn_mfma_f32_16x16x32_bf16(
                        a[mf], bc[nf], acc[mf][nf], 0, 0, 0);
            #pragma unroll
            for (int nf = 0; nf < 4; ++nf) bc[nf] = bn[nf];
        }
    }
    __syncthreads();   // [4] all ldsA reads done; safe to overwrite with h1

    // ------- phase 4: h1 = relu(acc + b1) -> bf16 -> ldsA in A-frag layout -------
    // elem (row=mf*16+lk*4+r, col=w*64+nf*16+l15):
    //   kb2 = 2w + (nf>>1); lane2 = lk*4+r + 16*((nf&1)*2 + (l15>>3)); j = l15&7
    #pragma unroll
    for (int nf = 0; nf < 4; ++nf) {
        const int col = w * 64 + nf * 16 + l15;
        const float bv = b1[col];
        const int kb2   = 2 * w + (nf >> 1);
        const int lane2 = lk * 4 + 16 * ((nf & 1) * 2 + (l15 >> 3));
        #pragma unroll
        for (int mf = 0; mf < 4; ++mf) {
            #pragma unroll
            for (int r = 0; r < 4; ++r) {
                float v = fmaxf(acc[mf][nf][r] + bv, 0.f);
                ldsA[((kb2 * 4 + mf) * 64 + lane2 + r) * 8 + (l15 & 7)] = f2bf_hw(v);
            }
        }
    }
    __syncthreads();   // [5] h1 tile complete

    // ---------------- phase 5: GEMM2 k-loop, barrier-free ----------------
    f32x4 acc2[4][4];
    #pragma unroll
    for (int mf = 0; mf < 4; ++mf)
        #pragma unroll
        for (int nf = 0; nf < 4; ++nf)
            acc2[mf][nf] = f32x4{0.f, 0.f, 0.f, 0.f};

    {
        bf16x8 bc[4], bn[4];
        #pragma unroll
        for (int nf = 0; nf < 4; ++nf)
            bc[nf] = *(const bf16x8*)(w2p + nf * 512);
        #pragma unroll
        for (int kb = 0; kb < 8; ++kb) {
            if (kb < 7) {
                #pragma unroll
                for (int nf = 0; nf < 4; ++nf)
                    bn[nf] = *(const bf16x8*)(w2p + (size_t)(kb + 1) * 8192 + nf * 512);
            }
            bf16x8 a[4];
            #pragma unroll
            for (int mf = 0; mf < 4; ++mf)
                a[mf] = *(const bf16x8*)&ldsA[((kb * 4 + mf) * 64 + lane) * 8];
            #pragma unroll
            for (int mf = 0; mf < 4; ++mf)
                #pragma unroll
                for (int nf = 0; nf < 4; ++nf)
                    acc2[mf][nf] = __builtin_amdgcn_mfma_f32_16x16x32_bf16(
                        a[mf], bc[nf], acc2[mf][nf], 0, 0, 0);
            #pragma unroll
            for (int nf = 0; nf < 4; ++nf) bc[nf] = bn[nf];
        }
    }

    // epilogue: out = relu(acc2 + b2), f32
    const int rbase = bm * 64 + lk * 4;
    const int cbase = w * 64 + l15;
    #pragma unroll
    for (int nf = 0; nf < 4; ++nf) {
        const int col = cbase + nf * 16;
        const float bv = b2[col];
        #pragma unroll
        for (int mf = 0; mf < 4; ++mf) {
            #pragma unroll
            for (int r = 0; r < 4; ++r) {
                float v = fmaxf(acc2[mf][nf][r] + bv, 0.f);
                out[(size_t)(rbase + mf * 16 + r) * HD + col] = v;
            }
        }
    }
}

extern "C" void kernel_launch(void* const* d_in, const int* in_sizes, int n_in,
                              void* d_out, int out_size, void* d_ws, size_t ws_size,
                              hipStream_t stream)
{
    const float* x        = (const float*)d_in[0];
    const float* pos      = (const float*)d_in[1];
    const float* x_skip   = (const float*)d_in[2];
    const float* pos_skip = (const float*)d_in[3];
    const float* W1       = (const float*)d_in[4];
    const float* b1       = (const float*)d_in[5];
    const float* W2       = (const float*)d_in[6];
    const float* b2       = (const float*)d_in[7];
    float* out = (float*)d_out;

    char* ws = (char*)d_ws;
    unsigned short* W1f  = (unsigned short*)(ws + W1F_OFF);
    unsigned short* W2f  = (unsigned short*)(ws + W2F_OFF);

    prep_kernel<<<PREP_B1 + PREP_B2 + PREP_B3, 256, 0, stream>>>(
        W1, W2, pos_skip, W1f, W2f, out);
    fp_fused_kernel<<<MTOT / 64, 256, 0, stream>>>(
        x, x_skip, pos, pos_skip, W1f, W2f, b1, b2, out);
}